// Round 1
// baseline (191.657 us; speedup 1.0000x reference)
//
#include <hip/hip_runtime.h>

#define OUT_F 11008
#define IN_F  4096
#define PKW   2048   // int32 words per weight row (each word = 1 byte = 2 nibbles)
#define BLKQ  128

typedef __attribute__((ext_vector_type(8))) short          s16x8;
typedef __attribute__((ext_vector_type(8))) unsigned short u16x8;
typedef __attribute__((ext_vector_type(4))) float          f32x4;
typedef __attribute__((ext_vector_type(4))) int            i32x4;

__device__ __forceinline__ unsigned short f2bf(float f) {
    union { float f; unsigned u; } v; v.f = f;
    unsigned r = v.u + 0x8000u + ((v.u >> 16) & 1u);   // RNE-ish
    return (unsigned short)(r >> 16);
}

// Pre-swizzle x (64x4096 f32) into MFMA A-fragment order (bf16):
//   xf[((kb*4 + mt)*64 + lane)*8 + i] = x[mt*16 + (lane&15)][kb*32 + (lane>>4)*8 + i]
__global__ void prep_xfrag(const float* __restrict__ x, unsigned short* __restrict__ xf) {
    int kb   = blockIdx.x;            // 0..127 (k-window of 32)
    int t    = threadIdx.x;           // 0..255
    int mt   = t >> 6;
    int lane = t & 63;
    int m  = mt * 16 + (lane & 15);
    int k0 = kb * 32 + (lane >> 4) * 8;
    const float* xp = x + m * IN_F + k0;
    f32x4 a = *(const f32x4*)(xp);
    f32x4 b = *(const f32x4*)(xp + 4);
    u16x8 v;
    v[0] = f2bf(a[0]); v[1] = f2bf(a[1]); v[2] = f2bf(a[2]); v[3] = f2bf(a[3]);
    v[4] = f2bf(b[0]); v[5] = f2bf(b[1]); v[6] = f2bf(b[2]); v[7] = f2bf(b[3]);
    *(u16x8*)(xf + (size_t)((kb * 4 + mt) * 64 + lane) * 8) = v;
}

// Main: one WG per 16 output columns. 4 waves split K into quarters of 1024.
// KEY CHANGE vs prior version: no LDS staging, no main-loop barriers.
// Each lane loads packed weights DIRECTLY in B-fragment layout
// (lane&15 = output col, lane>>4 = k-quad), dequants 4 dwords -> 8 bf16 in
// registers, and feeds MFMA. Weight loads are double-buffered in groups of
// 4 k-windows (~600+ cyc prefetch distance); A-fragments double-buffered
// 1 window ahead (L2-resident). LDS used only for the final 4-way K reduce.
__global__ __launch_bounds__(256) void qlin_main(
    const int*   __restrict__ wq,
    const float* __restrict__ scale,
    const float* __restrict__ zp,
    const float* __restrict__ bias,
    const unsigned short* __restrict__ xf,
    float* __restrict__ out)
{
    __shared__ float lsum[4 * 1024];   // 16 KB: 4 waves x (64 m x 16 col)

    const int t      = threadIdx.x;
    const int o_base = blockIdx.x * 16;
    const int wave   = t >> 6;        // K-quarter
    const int lane   = t & 63;
    const int o_r    = lane & 15;     // output col within tile (B-frag col)
    const int quad   = lane >> 4;     // k-quad within 32-k window
    const int o      = o_base + o_r;

    // per-lane dequant constants for this lane's k-positions:
    // j = (kb&3)*32 + quad*8 + i  (j = k mod 128)
    float s[4][8], zs[4][8];
    {
        const float* sp  = scale + (size_t)o * BLKQ + quad * 8;
        const float* zpp = zp    + (size_t)o * BLKQ + quad * 8;
        #pragma unroll
        for (int c4 = 0; c4 < 4; ++c4) {
            f32x4 s0 = *(const f32x4*)(sp  + c4 * 32);
            f32x4 s1 = *(const f32x4*)(sp  + c4 * 32 + 4);
            f32x4 z0 = *(const f32x4*)(zpp + c4 * 32);
            f32x4 z1 = *(const f32x4*)(zpp + c4 * 32 + 4);
            #pragma unroll
            for (int i = 0; i < 4; ++i) {
                s [c4][i]     = s0[i];  zs[c4][i]     = z0[i] * s0[i];
                s [c4][i + 4] = s1[i];  zs[c4][i + 4] = z1[i] * s1[i];
            }
        }
    }

    // weight base for this lane: row o, this wave's K-quarter, this quad's 4 dwords.
    // Per k-window kk (0..31): dwords wb[kk*16 .. kk*16+3] (16B, aligned).
    // Across 64 lanes one load = 16 rows x 64B contiguous -> fully coalesced.
    const int* wb = wq + (size_t)o * PKW + wave * 512 + quad * 4;
    const s16x8* xfv = (const s16x8*)xf;
    const int kb0 = wave * 32;

    f32x4 acc[4];
    #pragma unroll
    for (int mt = 0; mt < 4; ++mt) acc[mt] = (f32x4){0.f, 0.f, 0.f, 0.f};

    i32x4 wgrp[2][4];   // double-buffered weight groups (4 k-windows each)
    s16x8 af[2][4];     // double-buffered A-fragments (1 k-window ahead)

    #pragma unroll
    for (int cc = 0; cc < 4; ++cc) wgrp[0][cc] = *(const i32x4*)(wb + cc * 16);
    #pragma unroll
    for (int mt = 0; mt < 4; ++mt) af[0][mt] = xfv[(size_t)((kb0 * 4 + mt) * 64) + lane];

    #pragma unroll
    for (int g = 0; g < 8; ++g) {
        const int pg = g & 1;
        // prefetch next weight group (~4 windows = 600+ cyc ahead of use)
        if (g < 7) {
            const int* nb = wb + (g + 1) * 64;
            #pragma unroll
            for (int cc = 0; cc < 4; ++cc) wgrp[pg ^ 1][cc] = *(const i32x4*)(nb + cc * 16);
        }
        #pragma unroll
        for (int cc = 0; cc < 4; ++cc) {
            const int kk = g * 4 + cc;      // 0..31 ; kb = kb0 + kk ; kb&3 == cc
            const int pb = kk & 1;
            // prefetch next window's A-fragments (L2-resident xf)
            if (kk < 31) {
                const int kbn = kb0 + kk + 1;
                #pragma unroll
                for (int mt = 0; mt < 4; ++mt)
                    af[pb ^ 1][mt] = xfv[(size_t)((kbn * 4 + mt) * 64) + lane];
            }
            // in-register dequant: 4 dwords -> 8 bf16 B-fragment elements
            // (bit-identical math to the previous passing kernel)
            s16x8 bfr;
            #pragma unroll
            for (int d = 0; d < 4; ++d) {
                unsigned dw = (unsigned)wgrp[pg][cc][d];
                float fh = (float)((dw >> 4) & 15u);   // k even (high nibble first)
                float fl = (float)(dw & 15u);          // k odd
                bfr[2 * d]     = (short)f2bf(fmaf(fh, s[cc][2 * d],     -zs[cc][2 * d]));
                bfr[2 * d + 1] = (short)f2bf(fmaf(fl, s[cc][2 * d + 1], -zs[cc][2 * d + 1]));
            }
            #pragma unroll
            for (int mt = 0; mt < 4; ++mt)
                acc[mt] = __builtin_amdgcn_mfma_f32_16x16x32_bf16(af[pb][mt], bfr, acc[mt], 0, 0, 0);
        }
    }

    // 4-way K-quarter reduction via LDS, add bias, store
    #pragma unroll
    for (int mt = 0; mt < 4; ++mt) {
        #pragma unroll
        for (int r = 0; r < 4; ++r) {
            int m = mt * 16 + quad * 4 + r;      // C/D: col=lane&15, row=quad*4+reg
            lsum[wave * 1024 + m * 16 + o_r] = acc[mt][r];
        }
    }
    __syncthreads();
    #pragma unroll
    for (int p = 0; p < 4; ++p) {
        int e = p * 256 + t;
        int m = e >> 4, col = e & 15;
        float v = lsum[e] + lsum[1024 + e] + lsum[2048 + e] + lsum[3072 + e] + bias[o_base + col];
        out[(size_t)m * OUT_F + o_base + col] = v;
    }
}

extern "C" void kernel_launch(void* const* d_in, const int* in_sizes, int n_in,
                              void* d_out, int out_size, void* d_ws, size_t ws_size,
                              hipStream_t stream) {
    const float* x     = (const float*)d_in[0];
    const int*   wq    = (const int*)d_in[1];
    const float* scale = (const float*)d_in[2];
    const float* zpv   = (const float*)d_in[3];
    const float* bias  = (const float*)d_in[4];
    float* out = (float*)d_out;
    unsigned short* xf = (unsigned short*)d_ws;   // 512 KB A-fragment buffer

    prep_xfrag<<<128, 256, 0, stream>>>(x, xf);
    qlin_main<<<OUT_F / 16, 256, 0, stream>>>(wq, scale, zpv, bias, xf, out);
}

// Round 2
// 162.016 us; speedup vs baseline: 1.1830x; 1.1830x over previous
//
#include <hip/hip_runtime.h>

#define OUT_F 11008
#define IN_F  4096
#define PKW   2048   // int32 words per weight row (each word = 1 byte = 2 nibbles)
#define BLKQ  128

typedef __attribute__((ext_vector_type(8))) short          s16x8;
typedef __attribute__((ext_vector_type(8))) unsigned short u16x8;
typedef __attribute__((ext_vector_type(4))) float          f32x4;
typedef __attribute__((ext_vector_type(4))) int            i32x4;

__device__ __forceinline__ unsigned short f2bf(float f) {
    union { float f; unsigned u; } v; v.f = f;
    unsigned r = v.u + 0x8000u + ((v.u >> 16) & 1u);   // RNE-ish
    return (unsigned short)(r >> 16);
}

// Pre-swizzle x (64x4096 f32) into MFMA A-fragment order (bf16):
//   xf[((kb*4 + mt)*64 + lane)*8 + i] = x[mt*16 + (lane&15)][kb*32 + (lane>>4)*8 + i]
__global__ void prep_xfrag(const float* __restrict__ x, unsigned short* __restrict__ xf) {
    int kb   = blockIdx.x;            // 0..127 (k-window of 32)
    int t    = threadIdx.x;           // 0..255
    int mt   = t >> 6;
    int lane = t & 63;
    int m  = mt * 16 + (lane & 15);
    int k0 = kb * 32 + (lane >> 4) * 8;
    const float* xp = x + m * IN_F + k0;
    f32x4 a = *(const f32x4*)(xp);
    f32x4 b = *(const f32x4*)(xp + 4);
    u16x8 v;
    v[0] = f2bf(a[0]); v[1] = f2bf(a[1]); v[2] = f2bf(a[2]); v[3] = f2bf(a[3]);
    v[4] = f2bf(b[0]); v[5] = f2bf(b[1]); v[6] = f2bf(b[2]); v[7] = f2bf(b[3]);
    *(u16x8*)(xf + (size_t)((kb * 4 + mt) * 64 + lane) * 8) = v;
}

// Main: one WG per 16 output cols; 4 waves split K into quarters of 1024.
// Barrier-free main loop: each lane loads packed weights directly in
// B-fragment layout (lane&15 = col, lane>>4 = k-quad), dequants in registers,
// feeds MFMA. ALL array indices in the loop body are compile-time literals
// (named ping-pong buffers + macro-expanded group body) so nothing demotes
// to scratch — round-1's VGPR_Count=64 showed the compiler had demoted the
// runtime-parity-indexed buffers. Outer g-loop stays rolled; runtime g only
// in addresses.
__global__ __launch_bounds__(256, 3) void qlin_main(
    const int*   __restrict__ wq,
    const float* __restrict__ scale,
    const float* __restrict__ zp,
    const float* __restrict__ bias,
    const unsigned short* __restrict__ xf,
    float* __restrict__ out)
{
    __shared__ float lsum[4 * 1024];   // 16 KB: 4 waves x (64 m x 16 col)

    const int t      = threadIdx.x;
    const int o_base = blockIdx.x * 16;
    const int wave   = t >> 6;        // K-quarter
    const int lane   = t & 63;
    const int o_r    = lane & 15;     // output col within tile (B-frag col)
    const int quad   = lane >> 4;     // k-quad within 32-k window
    const int o      = o_base + o_r;

    // per-lane dequant constants: j = (kk&3)*32 + quad*8 + i   (j = k mod 128)
    float s[4][8], zs[4][8];
    {
        const float* sp  = scale + (size_t)o * BLKQ + quad * 8;
        const float* zpp = zp    + (size_t)o * BLKQ + quad * 8;
        #pragma unroll
        for (int c4 = 0; c4 < 4; ++c4) {
            f32x4 s0 = *(const f32x4*)(sp  + c4 * 32);
            f32x4 s1 = *(const f32x4*)(sp  + c4 * 32 + 4);
            f32x4 z0 = *(const f32x4*)(zpp + c4 * 32);
            f32x4 z1 = *(const f32x4*)(zpp + c4 * 32 + 4);
            #pragma unroll
            for (int i = 0; i < 4; ++i) {
                s [c4][i]     = s0[i];  zs[c4][i]     = z0[i] * s0[i];
                s [c4][i + 4] = s1[i];  zs[c4][i + 4] = z1[i] * s1[i];
            }
        }
    }

    // weight base: row o, this wave's K-quarter, this quad's 4 dwords.
    // window kk -> dwords wb[kk*16 .. kk*16+3]; one wave-wide load = 16 rows
    // x 64B contiguous (fully coalesced); a 4-window group covers 256B/row.
    const int* wb = wq + (size_t)o * PKW + wave * 512 + quad * 4;
    const s16x8* xfv = (const s16x8*)xf;
    const int kb0 = wave * 32;

    f32x4 acc[4];
    #pragma unroll
    for (int mt = 0; mt < 4; ++mt) acc[mt] = (f32x4){0.f, 0.f, 0.f, 0.f};

    i32x4 wgA[4], wgB[4];   // named ping-pong weight groups (4 windows each)
    s16x8 afA[4], afB[4];   // named ping-pong A-fragments (1 window ahead)

#define LOAD_WGRP(DST, GIDX) do {                                   \
        const int* nb_ = wb + (GIDX) * 64;                          \
        DST[0] = *(const i32x4*)(nb_);                              \
        DST[1] = *(const i32x4*)(nb_ + 16);                         \
        DST[2] = *(const i32x4*)(nb_ + 32);                         \
        DST[3] = *(const i32x4*)(nb_ + 48);                         \
    } while (0)

#define LOAD_AF(DST, KB) do {                                       \
        size_t b_ = (size_t)((KB) * 4) * 64 + lane;                 \
        DST[0] = xfv[b_];                                           \
        DST[1] = xfv[b_ + 64];                                      \
        DST[2] = xfv[b_ + 128];                                     \
        DST[3] = xfv[b_ + 192];                                     \
    } while (0)

    // One window: prefetch next A-frags (if DOPREF), dequant 4 dwords of
    // group W at literal window CC, run 4 MFMAs on current A-frags AFC.
#define DEQ_MFMA(W, CC, AFC, AFN, KBN, DOPREF) do {                              \
        if (DOPREF) LOAD_AF(AFN, (KBN));                                         \
        s16x8 bfr;                                                               \
        _Pragma("unroll")                                                        \
        for (int d = 0; d < 4; ++d) {                                            \
            unsigned dw = (unsigned)W[CC][d];                                    \
            float fh = (float)((dw >> 4) & 15u);   /* k even (high nibble) */    \
            float fl = (float)(dw & 15u);          /* k odd */                   \
            bfr[2 * d]     = (short)f2bf(fmaf(fh, s[CC][2 * d],     -zs[CC][2 * d]));     \
            bfr[2 * d + 1] = (short)f2bf(fmaf(fl, s[CC][2 * d + 1], -zs[CC][2 * d + 1])); \
        }                                                                        \
        acc[0] = __builtin_amdgcn_mfma_f32_16x16x32_bf16(AFC[0], bfr, acc[0], 0, 0, 0); \
        acc[1] = __builtin_amdgcn_mfma_f32_16x16x32_bf16(AFC[1], bfr, acc[1], 0, 0, 0); \
        acc[2] = __builtin_amdgcn_mfma_f32_16x16x32_bf16(AFC[2], bfr, acc[2], 0, 0, 0); \
        acc[3] = __builtin_amdgcn_mfma_f32_16x16x32_bf16(AFC[3], bfr, acc[3], 0, 0, 0); \
    } while (0)

    LOAD_WGRP(wgA, 0);
    LOAD_AF(afA, kb0);

    // g-loop stays ROLLED (4 iterations, 2 groups each); af parity is static
    // because each group starts at an even window index.
    for (int g = 0; g < 8; g += 2) {
        const int kw = kb0 + g * 4;
        LOAD_WGRP(wgB, g + 1);                    // 4-window prefetch distance
        DEQ_MFMA(wgA, 0, afA, afB, kw + 1, 1);
        DEQ_MFMA(wgA, 1, afB, afA, kw + 2, 1);
        DEQ_MFMA(wgA, 2, afA, afB, kw + 3, 1);
        DEQ_MFMA(wgA, 3, afB, afA, kw + 4, 1);
        if (g + 2 < 8) LOAD_WGRP(wgA, g + 2);
        DEQ_MFMA(wgB, 0, afA, afB, kw + 5, 1);
        DEQ_MFMA(wgB, 1, afB, afA, kw + 6, 1);
        DEQ_MFMA(wgB, 2, afA, afB, kw + 7, 1);
        DEQ_MFMA(wgB, 3, afB, afA, kw + 8, (g + 2 < 8));
    }
#undef LOAD_WGRP
#undef LOAD_AF
#undef DEQ_MFMA

    // 4-way K-quarter reduction via LDS, add bias, store
    #pragma unroll
    for (int mt = 0; mt < 4; ++mt) {
        #pragma unroll
        for (int r = 0; r < 4; ++r) {
            int m = mt * 16 + quad * 4 + r;      // C/D: col=lane&15, row=quad*4+reg
            lsum[wave * 1024 + m * 16 + o_r] = acc[mt][r];
        }
    }
    __syncthreads();
    #pragma unroll
    for (int p = 0; p < 4; ++p) {
        int e = p * 256 + t;
        int m = e >> 4, col = e & 15;
        float v = lsum[e] + lsum[1024 + e] + lsum[2048 + e] + lsum[3072 + e] + bias[o_base + col];
        out[(size_t)m * OUT_F + o_base + col] = v;
    }
}

extern "C" void kernel_launch(void* const* d_in, const int* in_sizes, int n_in,
                              void* d_out, int out_size, void* d_ws, size_t ws_size,
                              hipStream_t stream) {
    const float* x     = (const float*)d_in[0];
    const int*   wq    = (const int*)d_in[1];
    const float* scale = (const float*)d_in[2];
    const float* zpv   = (const float*)d_in[3];
    const float* bias  = (const float*)d_in[4];
    float* out = (float*)d_out;
    unsigned short* xf = (unsigned short*)d_ws;   // 512 KB A-fragment buffer

    prep_xfrag<<<128, 256, 0, stream>>>(x, xf);
    qlin_main<<<OUT_F / 16, 256, 0, stream>>>(wq, scale, zpv, bias, xf, out);
}